// Round 10
// baseline (311.150 us; speedup 1.0000x reference)
//
#include <hip/hip_runtime.h>
#include <hip/hip_bf16.h>

#define M_ROWS 16384
#define N_IN   512
#define N_HID  1024
#define K_TOT  1536   // 512 + 1024
#define N_TOT  4096   // 4 gates * 1024
#define NT     48     // K tiles of BK=32

typedef __attribute__((ext_vector_type(4))) float f32x4;
typedef __attribute__((ext_vector_type(8))) short bf16x8;
typedef __attribute__((ext_vector_type(4))) int   i32x4;

__device__ __forceinline__ ushort f2bf(float f) {
    union { float f; unsigned u; } un; un.f = f;
    unsigned u = un.u;
    u += 0x7fffu + ((u >> 16) & 1u);   // RNE
    return (ushort)(u >> 16);
}

__device__ __forceinline__ bf16x8 as_bf(i32x4 v) {
    union { i32x4 i; bf16x8 b; } u; u.i = v; return u.b;
}

// ---------------- prep kernels ----------------

__global__ void build_A(const float* __restrict__ x, const float* __restrict__ h,
                        ushort* __restrict__ A) {
    const int total = M_ROWS * K_TOT / 4;
    for (int p = blockIdx.x * blockDim.x + threadIdx.x; p < total;
         p += gridDim.x * blockDim.x) {
        int flat = p * 4;
        int row = flat / K_TOT;
        int col = flat - row * K_TOT;
        const float* src = (col < N_IN)
            ? (x + (size_t)row * N_IN + col)
            : (h + (size_t)row * N_HID + (col - N_IN));
        float4 v = *(const float4*)src;
        ushort4 o;
        o.x = f2bf(v.x); o.y = f2bf(v.y); o.z = f2bf(v.z); o.w = f2bf(v.w);
        *(ushort4*)(A + flat) = o;
    }
}

// W_perm row p (R2-validated map): grp = p>>7, cc = (p>>6)&1, g = (p>>4)&3,
// u = p&15.  source row j = grp*32 + cc*16 + u of gate g; k<512 -> Wx_g.
__global__ void build_W(const float* __restrict__ Wii, const float* __restrict__ Wif,
                        const float* __restrict__ Wig, const float* __restrict__ Wio,
                        const float* __restrict__ Whi, const float* __restrict__ Whf,
                        const float* __restrict__ Whg, const float* __restrict__ Who,
                        ushort* __restrict__ Wp) {
    const int total = N_TOT * K_TOT / 4;
    for (int p = blockIdx.x * blockDim.x + threadIdx.x; p < total;
         p += gridDim.x * blockDim.x) {
        int flat = p * 4;
        int prow = flat / K_TOT;
        int col = flat - prow * K_TOT;
        int grp = prow >> 7;
        int tt = prow & 127;
        int cc = (tt >> 6) & 1;
        int ss = tt & 63;
        int g  = ss >> 4;
        int u  = ss & 15;
        int j  = grp * 32 + cc * 16 + u;
        const float* src;
        if (col < N_IN) {
            const float* Wx = (g == 0) ? Wii : (g == 1) ? Wif : (g == 2) ? Wig : Wio;
            src = Wx + (size_t)j * N_IN + col;
        } else {
            const float* Wh = (g == 0) ? Whi : (g == 1) ? Whf : (g == 2) ? Whg : Who;
            src = Wh + (size_t)j * N_HID + (col - N_IN);
        }
        float4 v = *(const float4*)src;
        ushort4 o;
        o.x = f2bf(v.x); o.y = f2bf(v.y); o.z = f2bf(v.z); o.w = f2bf(v.w);
        *(ushort4*)(Wp + flat) = o;
    }
}

__global__ void build_bias(const float* __restrict__ bii, const float* __restrict__ bif,
                           const float* __restrict__ big, const float* __restrict__ bio,
                           const float* __restrict__ bhi, const float* __restrict__ bhf,
                           const float* __restrict__ bhg, const float* __restrict__ bho,
                           float* __restrict__ bias) {
    int n = blockIdx.x * blockDim.x + threadIdx.x;
    if (n >= N_TOT) return;
    int g = n >> 10, j = n & 1023;
    const float* bx = (g == 0) ? bii : (g == 1) ? bif : (g == 2) ? big : bio;
    const float* bh = (g == 0) ? bhi : (g == 1) ? bhf : (g == 2) ? bhg : bho;
    bias[n] = bx[j] + bh[j];
}

// ---------------- 128x128 rotated-pipeline GEMM + LSTM epilogue ----------
// R7's verified machinery (4-buf rotate, asm ds_read + counted lgkmcnt,
// vmcnt ledger, 0-conflict swizzle) at 128x128/4-wave geometry so TWO
// independent blocks fit per CU (64 KB LDS) -> cross-block pipe overlap
// (m114): one block's MFMA covers the other's barrier/vmcnt drains and
// epilogue. Ledger (4 VMEM/tile): at end of tile t outstanding =
// {stage(t+3):4, stage(t+2):4}; VMC(4) retires stage(t+2) -> buf complete
// one tile before its READS. lgkmcnt(8): the 8 just-issued reads (t+1)
// stay in flight through MFMA(t); older 8 are complete.

__device__ __forceinline__ float sigmoid_f(float z) {
    return 1.f / (1.f + __expf(-z));
}
__device__ __forceinline__ float tanh_f(float z) {
    z = fminf(fmaxf(z, -15.f), 15.f);
    float e = __expf(2.f * z);
    return (e - 1.f) / (e + 1.f);
}

__global__ __launch_bounds__(256, 2) void lstm_gemm(
        const ushort* __restrict__ A, const ushort* __restrict__ W,
        const float* __restrict__ bias, const float* __restrict__ cin,
        float* __restrict__ outc, float* __restrict__ outh) {
    __shared__ ushort sA[4][128 * 32];   // 4 x 8 KB
    __shared__ ushort sB[4][128 * 32];   // 4 x 8 KB  (64 KB total)

    const int tid  = threadIdx.x;
    const int wid  = tid >> 6;
    const int lane = tid & 63;
    const int wr = wid >> 1;     // 0..1 M half (64 rows)
    const int wc = wid & 1;      // 0..1 N half (64 cols = 4 gates x 16)
    const int m0 = blockIdx.x * 128;
    const int n0 = blockIdx.y * 128;

    f32x4 acc[4][4] = {};

    // staging: 256 thr x 16B = 64 rows/call; row = tid>>2 (0..63),
    // global chunk = (tid&3)^((tid>>3)&3)  [validated involution]
    const int srow = tid >> 2;
    const int fch  = (tid & 3) ^ ((tid >> 3) & 3);
    const ushort* gA = A + (size_t)(m0 + srow) * K_TOT + fch * 8;
    const ushort* gB = W + (size_t)(n0 + srow) * K_TOT + fch * 8;

#define GLDS(gptr, lptr) __builtin_amdgcn_global_load_lds(                     \
        (const __attribute__((address_space(1))) void*)(gptr),                 \
        (__attribute__((address_space(3))) void*)(lptr), 16, 0, 0)

#define STAGE(db, kt) do {                                                     \
    GLDS(gA + (size_t)(kt) * 32,                      &sA[db][tid * 8]);       \
    GLDS(gA + (size_t)64 * K_TOT + (size_t)(kt) * 32, &sA[db][2048 + tid * 8]); \
    GLDS(gB + (size_t)(kt) * 32,                      &sB[db][tid * 8]);       \
    GLDS(gB + (size_t)64 * K_TOT + (size_t)(kt) * 32, &sB[db][2048 + tid * 8]); \
} while (0)

    const int lrow = lane & 15;
    const int cb0  = lane >> 4;             // 0..3 k-chunk
    const int csw  = (lrow >> 1) & 3;       // read swizzle (0-conflict, R7)
    const unsigned aByte = (unsigned)(((wr * 64 + lrow) * 32 + ((cb0 ^ csw) * 8)) * 2);
    const unsigned bByte = (unsigned)(((wc * 64 + lrow) * 32 + ((cb0 ^ csw) * 8)) * 2);

#define DSR(dst, addr, IMM) asm volatile(                                      \
    "ds_read_b128 %0, %1 offset:" IMM : "=&v"(dst) : "v"(addr))

// 8 asm ds_reads: 4 A frags (imm mi*1024 = 16 rows) + 4 B frags (ni*1024)
#define READS(afX, bfX, db) do {                                               \
    unsigned aAd = (unsigned)(uintptr_t)                                       \
        (__attribute__((address_space(3))) ushort*)&sA[db][0] + aByte;         \
    unsigned bAd = (unsigned)(uintptr_t)                                       \
        (__attribute__((address_space(3))) ushort*)&sB[db][0] + bByte;         \
    DSR(afX[0], aAd, "0");    DSR(afX[1], aAd, "1024");                        \
    DSR(afX[2], aAd, "2048"); DSR(afX[3], aAd, "3072");                        \
    DSR(bfX[0], bAd, "0");    DSR(bfX[1], bAd, "1024");                        \
    DSR(bfX[2], bAd, "2048"); DSR(bfX[3], bAd, "3072");                        \
} while (0)

#define WAITK(n) do {                                                          \
    asm volatile("s_waitcnt lgkmcnt(" #n ")");                                 \
    __builtin_amdgcn_sched_barrier(0);                                         \
} while (0)

#define MFMAS(afX, bfX) do {                                                   \
    __builtin_amdgcn_s_setprio(1);                                             \
    _Pragma("unroll")                                                          \
    for (int m = 0; m < 4; ++m)                                                \
        _Pragma("unroll")                                                      \
        for (int n = 0; n < 4; ++n)                                            \
            acc[m][n] = __builtin_amdgcn_mfma_f32_16x16x32_bf16(               \
                as_bf(afX[m]), as_bf(bfX[n]), acc[m][n], 0, 0, 0);             \
    __builtin_amdgcn_s_setprio(0);                                             \
} while (0)

#define BARX() __builtin_amdgcn_s_barrier()
#define VMC(n) asm volatile("s_waitcnt vmcnt(" #n ")" ::: "memory")

    i32x4 af0[4], bf0[4], af1[4], bf1[4];

    // prologue: stage tiles 0,1,2 (12 loads); VMC(4) retires 0,1; read t0
    STAGE(0, 0); STAGE(1, 1); STAGE(2, 2);
    VMC(4);
    BARX();
    READS(af0, bf0, 0);

    // tile t: STAGE(t+3) | READS(t+1) | lgkm(8) | MFMA(t) | VMC(4) | BAR
#define TILE(u, t, FnA, FnB, FcA, FcB) do {                                    \
    STAGE(((u) + 3) & 3, (t) + 3);                                             \
    READS(FnA, FnB, ((u) + 1) & 3);                                            \
    WAITK(8);                                                                  \
    MFMAS(FcA, FcB);                                                           \
    VMC(4);                                                                    \
    BARX();                                                                    \
} while (0)

    for (int hh = 0; hh < 11; ++hh) {
        const int t = hh * 4;
        TILE(0, t + 0, af1, bf1, af0, bf0);
        TILE(1, t + 1, af0, bf0, af1, bf1);
        TILE(2, t + 2, af1, bf1, af0, bf0);
        TILE(3, t + 3, af0, bf0, af1, bf1);
    }
    // peeled tail: t = 44..47
    TILE(0, 44, af1, bf1, af0, bf0);            // stages 47
    // t=45: no stage; VMC(0) retires stage(47) before t=46 reads buf3
    READS(af0, bf0, 2);                         // tile 46 frags
    WAITK(8);
    MFMAS(af1, bf1);                            // tile 45
    VMC(0);
    BARX();
    // t=46
    READS(af1, bf1, 3);                         // tile 47 frags
    WAITK(8);
    MFMAS(af0, bf0);                            // tile 46
    BARX();
    // t=47
    WAITK(0);
    MFMAS(af1, bf1);                            // tile 47

    // epilogue: lane owns unit = grp*32 + wc*16 + lrow (R2-validated map)
    const int unit = blockIdx.y * 32 + wc * 16 + lrow;
    const float b0 = bias[unit];
    const float b1 = bias[1024 + unit];
    const float b2 = bias[2048 + unit];
    const float b3 = bias[3072 + unit];
    const int r0 = m0 + wr * 64 + (lane >> 4) * 4;
#pragma unroll
    for (int mi = 0; mi < 4; ++mi) {
#pragma unroll
        for (int q = 0; q < 4; ++q) {
            const int row = r0 + mi * 16 + q;
            const size_t off = (size_t)row * N_HID + unit;
            float zi = acc[mi][0][q] + b0;
            float zf = acc[mi][1][q] + b1;
            float zg = acc[mi][2][q] + b2;
            float zo = acc[mi][3][q] + b3;
            float it_ = sigmoid_f(zi);
            float ft = sigmoid_f(zf);
            float gt = tanh_f(zg);
            float ot = sigmoid_f(zo);
            float ct = ft * cin[off] + it_ * gt;
            float ht = ot * tanh_f(ct);
            outc[off] = ct;
            outh[off] = ht;
        }
    }
#undef GLDS
#undef STAGE
#undef DSR
#undef READS
#undef WAITK
#undef MFMAS
#undef BARX
#undef VMC
#undef TILE
}

// ---------------- launch ----------------

extern "C" void kernel_launch(void* const* d_in, const int* in_sizes, int n_in,
                              void* d_out, int out_size, void* d_ws, size_t ws_size,
                              hipStream_t stream) {
    const float* x = (const float*)d_in[0];
    const float* c = (const float*)d_in[1];
    const float* h = (const float*)d_in[2];
    const float* Wii = (const float*)d_in[3];  const float* bii = (const float*)d_in[4];
    const float* Wif = (const float*)d_in[5];  const float* bif = (const float*)d_in[6];
    const float* Wig = (const float*)d_in[7];  const float* big = (const float*)d_in[8];
    const float* Wio = (const float*)d_in[9];  const float* bio = (const float*)d_in[10];
    const float* Whi = (const float*)d_in[11]; const float* bhi = (const float*)d_in[12];
    const float* Whf = (const float*)d_in[13]; const float* bhf = (const float*)d_in[14];
    const float* Whg = (const float*)d_in[15]; const float* bhg = (const float*)d_in[16];
    const float* Who = (const float*)d_in[17]; const float* bho = (const float*)d_in[18];

    char* ws = (char*)d_ws;
    ushort* A_cat  = (ushort*)ws;                                   // 50,331,648 B
    ushort* W_perm = (ushort*)(ws + (size_t)M_ROWS * K_TOT * 2);    // 12,582,912 B
    float*  biasc  = (float*)(ws + (size_t)M_ROWS * K_TOT * 2
                                 + (size_t)N_TOT * K_TOT * 2);      // 16 KB

    float* outc = (float*)d_out;
    float* outh = (float*)d_out + (size_t)M_ROWS * N_HID;

    hipLaunchKernelGGL(build_A, dim3(2048), dim3(256), 0, stream, x, h, A_cat);
    hipLaunchKernelGGL(build_W, dim3(1024), dim3(256), 0, stream,
                       Wii, Wif, Wig, Wio, Whi, Whf, Whg, Who, W_perm);
    hipLaunchKernelGGL(build_bias, dim3(16), dim3(256), 0, stream,
                       bii, bif, big, bio, bhi, bhf, bhg, bho, biasc);
    hipLaunchKernelGGL(lstm_gemm, dim3(M_ROWS / 128, N_TOT / 128), dim3(256), 0, stream,
                       A_cat, W_perm, biasc, c, outc, outh);
}

// Round 11
// 306.066 us; speedup vs baseline: 1.0166x; 1.0166x over previous
//
#include <hip/hip_runtime.h>
#include <hip/hip_bf16.h>

#define M_ROWS 16384
#define N_IN   512
#define N_HID  1024
#define K_TOT  1536   // 512 + 1024
#define N_TOT  4096   // 4 gates * 1024
#define NT     48     // K tiles of BK=32

typedef __attribute__((ext_vector_type(4))) float f32x4;
typedef __attribute__((ext_vector_type(8))) short bf16x8;
typedef __attribute__((ext_vector_type(4))) int   i32x4;

__device__ __forceinline__ ushort f2bf(float f) {
    union { float f; unsigned u; } un; un.f = f;
    unsigned u = un.u;
    u += 0x7fffu + ((u >> 16) & 1u);   // RNE
    return (ushort)(u >> 16);
}

__device__ __forceinline__ bf16x8 as_bf(i32x4 v) {
    union { i32x4 i; bf16x8 b; } u; u.i = v; return u.b;
}

// ---------------- prep kernels ----------------

__global__ void build_A(const float* __restrict__ x, const float* __restrict__ h,
                        ushort* __restrict__ A) {
    const int total = M_ROWS * K_TOT / 4;
    for (int p = blockIdx.x * blockDim.x + threadIdx.x; p < total;
         p += gridDim.x * blockDim.x) {
        int flat = p * 4;
        int row = flat / K_TOT;
        int col = flat - row * K_TOT;
        const float* src = (col < N_IN)
            ? (x + (size_t)row * N_IN + col)
            : (h + (size_t)row * N_HID + (col - N_IN));
        float4 v = *(const float4*)src;
        ushort4 o;
        o.x = f2bf(v.x); o.y = f2bf(v.y); o.z = f2bf(v.z); o.w = f2bf(v.w);
        *(ushort4*)(A + flat) = o;
    }
}

// W_perm row p: bn = p>>8 (256 rows per block-col), wcn = (r>>6)&3,
// g = (r>>4)&3, u = r&15.  source row j = bn*64 + wcn*16 + u of gate g.
__global__ void build_W(const float* __restrict__ Wii, const float* __restrict__ Wif,
                        const float* __restrict__ Wig, const float* __restrict__ Wio,
                        const float* __restrict__ Whi, const float* __restrict__ Whf,
                        const float* __restrict__ Whg, const float* __restrict__ Who,
                        ushort* __restrict__ Wp) {
    const int total = N_TOT * K_TOT / 4;
    for (int p = blockIdx.x * blockDim.x + threadIdx.x; p < total;
         p += gridDim.x * blockDim.x) {
        int flat = p * 4;
        int prow = flat / K_TOT;
        int col = flat - prow * K_TOT;
        int bn  = prow >> 8;
        int r   = prow & 255;
        int wcn = r >> 6;
        int g   = (r >> 4) & 3;
        int u   = r & 15;
        int j   = bn * 64 + wcn * 16 + u;
        const float* src;
        if (col < N_IN) {
            const float* Wx = (g == 0) ? Wii : (g == 1) ? Wif : (g == 2) ? Wig : Wio;
            src = Wx + (size_t)j * N_IN + col;
        } else {
            const float* Wh = (g == 0) ? Whi : (g == 1) ? Whf : (g == 2) ? Whg : Who;
            src = Wh + (size_t)j * N_HID + (col - N_IN);
        }
        float4 v = *(const float4*)src;
        ushort4 o;
        o.x = f2bf(v.x); o.y = f2bf(v.y); o.z = f2bf(v.z); o.w = f2bf(v.w);
        *(ushort4*)(Wp + flat) = o;
    }
}

__global__ void build_bias(const float* __restrict__ bii, const float* __restrict__ bif,
                           const float* __restrict__ big, const float* __restrict__ bio,
                           const float* __restrict__ bhi, const float* __restrict__ bhf,
                           const float* __restrict__ bhg, const float* __restrict__ bho,
                           float* __restrict__ bias) {
    int n = blockIdx.x * blockDim.x + threadIdx.x;
    if (n >= N_TOT) return;
    int g = n >> 10, j = n & 1023;
    const float* bx = (g == 0) ? bii : (g == 1) ? bif : (g == 2) ? big : bio;
    const float* bh = (g == 0) ? bhi : (g == 1) ? bhf : (g == 2) ? bhg : bho;
    bias[n] = bx[j] + bh[j];
}

// ---------------- fully-asm-pipelined GEMM + LSTM epilogue ----------------
// R7 skeleton (256x256, BK=32, 8 waves, 4-buf rotate, counted lgkm/vmcnt)
// with staging converted to inline-asm global_load_lds_dwordx4 (LDS dest via
// M0). Rationale: the intrinsic form is compiler-tracked and gets an
// auto-inserted vmcnt(0) before every s_barrier (LDS-write visibility),
// which re-drains the queue downstream of our counted VMC(4) and puts full
// L2/HBM latency on every tile. With asm loads + raw barriers, the hand
// ledger governs:
//   stage(t+3) issued at t; at end of t outstanding = {S(t+3):4, S(t+2):4};
//   VMC(4) retires S(t+2); barrier -> buf(t+2) complete for all waves one
//   tile before its reads. Reads for t+1 issued during t; lgkmcnt(12)
//   before MFMA(t) leaves them in flight (DS completes in-order).
// M0 invariant: restored to -1 after each stage batch.

__device__ __forceinline__ float sigmoid_f(float z) {
    return 1.f / (1.f + __expf(-z));
}
__device__ __forceinline__ float tanh_f(float z) {
    z = fminf(fmaxf(z, -15.f), 15.f);
    float e = __expf(2.f * z);
    return (e - 1.f) / (e + 1.f);
}

__global__ __launch_bounds__(512, 1) void lstm_gemm(
        const ushort* __restrict__ A, const ushort* __restrict__ W,
        const float* __restrict__ bias, const float* __restrict__ cin,
        float* __restrict__ outc, float* __restrict__ outh) {
    __shared__ ushort sA[4][256 * 32];   // 4 x 16 KB
    __shared__ ushort sB[4][256 * 32];   // 4 x 16 KB  (128 KB total)

    const int tid  = threadIdx.x;
    const int wid  = tid >> 6;
    const int lane = tid & 63;
    const int wr  = wid >> 2;    // 0..1  M half
    const int wcn = wid & 3;     // 0..3  N quarter (64 cols)
    const int m0 = blockIdx.x * 256;
    const int n0 = blockIdx.y * 256;

    f32x4 acc[8][4] = {};

    // staging map (validated): row = tid>>2 (0..127), global chunk =
    // (tid&3)^((tid>>3)&3); call i adds 128 rows (+393216 B).
    const int srow = tid >> 2;
    const int fch  = (tid & 3) ^ ((tid >> 3) & 3);
    const uint64_t gAu = (uint64_t)(uintptr_t)(A + (size_t)(m0 + srow) * K_TOT + fch * 8);
    const uint64_t gBu = (uint64_t)(uintptr_t)(W + (size_t)(n0 + srow) * K_TOT + fch * 8);

    // wave-uniform M0 bases: lds_dst(lane) = M0 + lane*16
    const unsigned sAb = (unsigned)(uintptr_t)
        (__attribute__((address_space(3))) ushort*)&sA[0][0];
    const unsigned sBb = (unsigned)(uintptr_t)
        (__attribute__((address_space(3))) ushort*)&sB[0][0];
    unsigned m0A[4], m0B[4];
#pragma unroll
    for (int d = 0; d < 4; ++d) {
        m0A[d] = __builtin_amdgcn_readfirstlane(sAb + d * 16384 + wid * 1024);
        m0B[d] = __builtin_amdgcn_readfirstlane(sBb + d * 16384 + wid * 1024);
    }

// 4 asm LDS-DMA loads (2 A halves + 2 B halves); M0 selects LDS dest.
#define STAGE(db, kt) do {                                                     \
    uint64_t a0_ = gAu + (uint64_t)(kt) * 64;                                  \
    uint64_t a1_ = a0_ + 393216u;                                              \
    uint64_t b0_ = gBu + (uint64_t)(kt) * 64;                                  \
    uint64_t b1_ = b0_ + 393216u;                                              \
    asm volatile(                                                              \
        "s_mov_b32 m0, %4\n\t"                                                 \
        "global_load_lds_dwordx4 %0, off\n\t"                                  \
        "s_mov_b32 m0, %5\n\t"                                                 \
        "global_load_lds_dwordx4 %1, off\n\t"                                  \
        "s_mov_b32 m0, %6\n\t"                                                 \
        "global_load_lds_dwordx4 %2, off\n\t"                                  \
        "s_mov_b32 m0, %7\n\t"                                                 \
        "global_load_lds_dwordx4 %3, off\n\t"                                  \
        "s_mov_b32 m0, -1"                                                     \
        :: "v"(a0_), "v"(a1_), "v"(b0_), "v"(b1_),                             \
           "s"(m0A[db]), "s"(m0A[db] + 8192u),                                 \
           "s"(m0B[db]), "s"(m0B[db] + 8192u));                                \
} while (0)

    const int lrow = lane & 15;
    const int cb0  = lane >> 4;             // 0..3 k-chunk
    const int csw2 = (lrow >> 1) & 3;       // read swizzle (0-conflict, R6/R7)
    const unsigned aByte = (unsigned)(((wr * 128 + lrow) * 32 + ((cb0 ^ csw2) * 8)) * 2);
    const unsigned bByte = (unsigned)(((wcn * 64  + lrow) * 32 + ((cb0 ^ csw2) * 8)) * 2);

#define DSR(dst, addr, IMM) asm volatile(                                      \
    "ds_read_b128 %0, %1 offset:" IMM : "=&v"(dst) : "v"(addr))

// 12 asm ds_reads: 8 A frags (imm mi*1024) + 4 B frags (imm ni*1024)
#define READS(afX, bfX, db) do {                                               \
    unsigned aAd = sAb + (unsigned)(db) * 16384u + aByte;                      \
    unsigned bAd = sBb + (unsigned)(db) * 16384u + bByte;                      \
    i32x4 r0, r1, r2, r3, r4, r5, r6, r7, s0, s1, s2, s3;                      \
    DSR(r0, aAd, "0");    DSR(r1, aAd, "1024");                                \
    DSR(r2, aAd, "2048"); DSR(r3, aAd, "3072");                                \
    DSR(r4, aAd, "4096"); DSR(r5, aAd, "5120");                                \
    DSR(r6, aAd, "6144"); DSR(r7, aAd, "7168");                                \
    DSR(s0, bAd, "0");    DSR(s1, bAd, "1024");                                \
    DSR(s2, bAd, "2048"); DSR(s3, bAd, "3072");                                \
    afX[0] = as_bf(r0); afX[1] = as_bf(r1); afX[2] = as_bf(r2);                \
    afX[3] = as_bf(r3); afX[4] = as_bf(r4); afX[5] = as_bf(r5);                \
    afX[6] = as_bf(r6); afX[7] = as_bf(r7);                                    \
    bfX[0] = as_bf(s0); bfX[1] = as_bf(s1); bfX[2] = as_bf(s2);                \
    bfX[3] = as_bf(s3);                                                        \
} while (0)

#define WAITK(n) do {                                                          \
    asm volatile("s_waitcnt lgkmcnt(" #n ")");                                 \
    __builtin_amdgcn_sched_barrier(0);                                         \
} while (0)

#define MFMAS(afX, bfX) do {                                                   \
    __builtin_amdgcn_s_setprio(1);                                             \
    _Pragma("unroll")                                                          \
    for (int m = 0; m < 8; ++m)                                                \
        _Pragma("unroll")                                                      \
        for (int n = 0; n < 4; ++n)                                            \
            acc[m][n] = __builtin_amdgcn_mfma_f32_16x16x32_bf16(               \
                afX[m], bfX[n], acc[m][n], 0, 0, 0);                           \
    __builtin_amdgcn_s_setprio(0);                                             \
} while (0)

#define BARX() __builtin_amdgcn_s_barrier()
#define VMC(n) asm volatile("s_waitcnt vmcnt(" #n ")" ::: "memory")

    bf16x8 af0[8], bfv0[4], af1[8], bfv1[4];

    // prologue: stage tiles 0,1,2 (12 loads); VMC(4) retires S0,S1; read t0
    STAGE(0, 0); STAGE(1, 1); STAGE(2, 2);
    VMC(4);
    BARX();
    READS(af0, bfv0, 0);

    // tile t: STAGE(t+3) | READS(t+1) | lgkm(12) | MFMA(t) | VMC(4) | BAR
#define TILE(u, t, Fna, Fnb, Fca, Fcb) do {                                    \
    STAGE(((u) + 3) & 3, (t) + 3);                                             \
    READS(Fna, Fnb, ((u) + 1) & 3);                                            \
    WAITK(12);                                                                 \
    MFMAS(Fca, Fcb);                                                           \
    VMC(4);                                                                    \
    BARX();                                                                    \
} while (0)

    for (int hh = 0; hh < 11; ++hh) {
        const int t = hh * 4;
        TILE(0, t + 0, af1, bfv1, af0, bfv0);
        TILE(1, t + 1, af0, bfv0, af1, bfv1);
        TILE(2, t + 2, af1, bfv1, af0, bfv0);
        TILE(3, t + 3, af0, bfv0, af1, bfv1);
    }
    // peeled tail: t = 44..47
    TILE(0, 44, af1, bfv1, af0, bfv0);          // stages 47
    // t=45: no stage; VMC(0) retires S47 before t=46 reads buf3
    READS(af0, bfv0, 2);                        // tile 46 frags
    WAITK(12);
    MFMAS(af1, bfv1);                           // tile 45
    VMC(0);
    BARX();
    // t=46
    READS(af1, bfv1, 3);                        // tile 47 frags
    WAITK(12);
    MFMAS(af0, bfv0);                           // tile 46
    BARX();
    // t=47
    WAITK(0);
    MFMAS(af1, bfv1);                           // tile 47

    // epilogue: lane owns unit = bn*64 + wcn*16 + lrow; gates = acc[m][0..3]
    const int unit = blockIdx.y * 64 + wcn * 16 + lrow;
    const float b0 = bias[unit];
    const float b1 = bias[1024 + unit];
    const float b2 = bias[2048 + unit];
    const float b3 = bias[3072 + unit];
    const int r0 = m0 + wr * 128 + (lane >> 4) * 4;
#pragma unroll
    for (int mi = 0; mi < 8; ++mi) {
#pragma unroll
        for (int q = 0; q < 4; ++q) {
            const int row = r0 + mi * 16 + q;
            const size_t off = (size_t)row * N_HID + unit;
            float zi = acc[mi][0][q] + b0;
            float zf = acc[mi][1][q] + b1;
            float zg = acc[mi][2][q] + b2;
            float zo = acc[mi][3][q] + b3;
            float it_ = sigmoid_f(zi);
            float ft = sigmoid_f(zf);
            float gt = tanh_f(zg);
            float ot = sigmoid_f(zo);
            float ct = ft * cin[off] + it_ * gt;
            float ht = ot * tanh_f(ct);
            outc[off] = ct;
            outh[off] = ht;
        }
    }
#undef STAGE
#undef DSR
#undef READS
#undef WAITK
#undef MFMAS
#undef BARX
#undef VMC
#undef TILE
}

// ---------------- launch ----------------

extern "C" void kernel_launch(void* const* d_in, const int* in_sizes, int n_in,
                              void* d_out, int out_size, void* d_ws, size_t ws_size,
                              hipStream_t stream) {
    const float* x = (const float*)d_in[0];
    const float* c = (const float*)d_in[1];
    const float* h = (const float*)d_in[2];
    const float* Wii = (const float*)d_in[3];  const float* bii = (const float*)d_in[4];
    const float* Wif = (const float*)d_in[5];  const float* bif = (const float*)d_in[6];
    const float* Wig = (const float*)d_in[7];  const float* big = (const float*)d_in[8];
    const float* Wio = (const float*)d_in[9];  const float* bio = (const float*)d_in[10];
    const float* Whi = (const float*)d_in[11]; const float* bhi = (const float*)d_in[12];
    const float* Whf = (const float*)d_in[13]; const float* bhf = (const float*)d_in[14];
    const float* Whg = (const float*)d_in[15]; const float* bhg = (const float*)d_in[16];
    const float* Who = (const float*)d_in[17]; const float* bho = (const float*)d_in[18];

    char* ws = (char*)d_ws;
    ushort* A_cat  = (ushort*)ws;                                   // 50,331,648 B
    ushort* W_perm = (ushort*)(ws + (size_t)M_ROWS * K_TOT * 2);    // 12,582,912 B
    float*  biasc  = (float*)(ws + (size_t)M_ROWS * K_TOT * 2
                                 + (size_t)N_TOT * K_TOT * 2);      // 16 KB

    float* outc = (float*)d_out;
    float* outh = (float*)d_out + (size_t)M_ROWS * N_HID;

    hipLaunchKernelGGL(build_A, dim3(2048), dim3(256), 0, stream, x, h, A_cat);
    hipLaunchKernelGGL(build_W, dim3(1024), dim3(256), 0, stream,
                       Wii, Wif, Wig, Wio, Whi, Whf, Whg, Who, W_perm);
    hipLaunchKernelGGL(build_bias, dim3(16), dim3(256), 0, stream,
                       bii, bif, big, bio, bhi, bhf, bhg, bho, biasc);
    hipLaunchKernelGGL(lstm_gemm, dim3(M_ROWS / 256, N_TOT / 256), dim3(512), 0, stream,
                       A_cat, W_perm, biasc, c, outc, outh);
}

// Round 12
// 270.529 us; speedup vs baseline: 1.1502x; 1.1314x over previous
//
#include <hip/hip_runtime.h>
#include <hip/hip_bf16.h>

#define M_ROWS 16384
#define N_IN   512
#define N_HID  1024
#define K_TOT  1536   // 512 + 1024
#define N_TOT  4096   // 4 gates * 1024
#define NT     48     // K tiles of BK=32

typedef __attribute__((ext_vector_type(4))) float f32x4;
typedef __attribute__((ext_vector_type(8))) short bf16x8;
typedef __attribute__((ext_vector_type(4))) int   i32x4;

__device__ __forceinline__ ushort f2bf(float f) {
    union { float f; unsigned u; } un; un.f = f;
    unsigned u = un.u;
    u += 0x7fffu + ((u >> 16) & 1u);   // RNE
    return (ushort)(u >> 16);
}

__device__ __forceinline__ bf16x8 as_bf(i32x4 v) {
    union { i32x4 i; bf16x8 b; } u; u.i = v; return u.b;
}

// ---------------- fused prep kernel ----------------
// One grid-stride kernel covering: A_cat build (x|h f32->bf16), W_perm
// build (gate-permuted, R7-validated map), bias combine. Saves 2 launch
// gaps; each sub-range is the byte-identical logic of the validated
// separate kernels.

__global__ void prep_all(const float* __restrict__ x, const float* __restrict__ h,
                         const float* __restrict__ Wii, const float* __restrict__ Wif,
                         const float* __restrict__ Wig, const float* __restrict__ Wio,
                         const float* __restrict__ Whi, const float* __restrict__ Whf,
                         const float* __restrict__ Whg, const float* __restrict__ Who,
                         const float* __restrict__ bii, const float* __restrict__ bif,
                         const float* __restrict__ big, const float* __restrict__ bio,
                         const float* __restrict__ bhi, const float* __restrict__ bhf,
                         const float* __restrict__ bhg, const float* __restrict__ bho,
                         ushort* __restrict__ A, ushort* __restrict__ Wp,
                         float* __restrict__ bias) {
    const int totalA = M_ROWS * K_TOT / 4;   // 6,291,456
    const int totalW = N_TOT * K_TOT / 4;    // 1,572,864
    const int totalE = totalA + totalW + N_TOT;
    const int stride = gridDim.x * blockDim.x;
    for (int p = blockIdx.x * blockDim.x + threadIdx.x; p < totalE; p += stride) {
        if (p < totalA) {
            int flat = p * 4;
            int row = flat / K_TOT;
            int col = flat - row * K_TOT;
            const float* src = (col < N_IN)
                ? (x + (size_t)row * N_IN + col)
                : (h + (size_t)row * N_HID + (col - N_IN));
            float4 v = *(const float4*)src;
            ushort4 o;
            o.x = f2bf(v.x); o.y = f2bf(v.y); o.z = f2bf(v.z); o.w = f2bf(v.w);
            *(ushort4*)(A + flat) = o;
        } else if (p < totalA + totalW) {
            int q = p - totalA;
            int flat = q * 4;
            int prow = flat / K_TOT;
            int col = flat - prow * K_TOT;
            int bn  = prow >> 8;
            int r   = prow & 255;
            int wcn = r >> 6;
            int g   = (r >> 4) & 3;
            int u   = r & 15;
            int j   = bn * 64 + wcn * 16 + u;
            const float* src;
            if (col < N_IN) {
                const float* Wx = (g == 0) ? Wii : (g == 1) ? Wif : (g == 2) ? Wig : Wio;
                src = Wx + (size_t)j * N_IN + col;
            } else {
                const float* Wh = (g == 0) ? Whi : (g == 1) ? Whf : (g == 2) ? Whg : Who;
                src = Wh + (size_t)j * N_HID + (col - N_IN);
            }
            float4 v = *(const float4*)src;
            ushort4 o;
            o.x = f2bf(v.x); o.y = f2bf(v.y); o.z = f2bf(v.z); o.w = f2bf(v.w);
            *(ushort4*)(Wp + flat) = o;
        } else {
            int n = p - totalA - totalW;
            int g = n >> 10, j = n & 1023;
            const float* bx = (g == 0) ? bii : (g == 1) ? bif : (g == 2) ? big : bio;
            const float* bh = (g == 0) ? bhi : (g == 1) ? bhf : (g == 2) ? bhg : bho;
            bias[n] = bx[j] + bh[j];
        }
    }
}

// ---------------- rotated-pipeline GEMM + LSTM epilogue (R7, verified) ----
// 256x256 block, BK=32, 48 K-tiles, 8 waves (2M x 4N), per-wave 128x64.
// 4 LDS buffers; register rotate (frags for t+1 ds_read during t, asm
// ds_read_b128 + counted lgkmcnt(12)); intrinsic global_load_lds staging,
// stage-ahead-3, VMC(4) retires buf(t+2) one tile before its reads.
// NEW (this round): XCD-aware 1D grid swizzle — XCD k owns x-stripe
// [8k, 8k+8); within the stripe consecutive ids iterate y with x fixed,
// so each A panel is fetched once per XCD and reused 16x from L2.

__device__ __forceinline__ float sigmoid_f(float z) {
    return 1.f / (1.f + __expf(-z));
}
__device__ __forceinline__ float tanh_f(float z) {
    z = fminf(fmaxf(z, -15.f), 15.f);
    float e = __expf(2.f * z);
    return (e - 1.f) / (e + 1.f);
}

__global__ __launch_bounds__(512, 1) void lstm_gemm(
        const ushort* __restrict__ A, const ushort* __restrict__ W,
        const float* __restrict__ bias, const float* __restrict__ cin,
        float* __restrict__ outc, float* __restrict__ outh) {
    __shared__ ushort sA[4][256 * 32];   // 4 x 16 KB
    __shared__ ushort sB[4][256 * 32];   // 4 x 16 KB  (128 KB total)

    const int tid  = threadIdx.x;
    const int wid  = tid >> 6;
    const int lane = tid & 63;
    const int wr  = wid >> 2;    // 0..1  M half
    const int wcn = wid & 3;     // 0..3  N quarter (64 cols)

    // XCD swizzle: lid -> (bx, by).  1024 blocks, 8 XCDs, lid&7 = XCD.
    // XCD k: x = k*8 + (j>>4), y = j&15  (j = lid>>3, 0..127)
    const int lid = blockIdx.x;
    const int xcd = lid & 7;
    const int j_  = lid >> 3;
    const int bx  = xcd * 8 + (j_ >> 4);
    const int by  = j_ & 15;
    const int m0 = bx * 256;
    const int n0 = by * 256;

    f32x4 acc[8][4] = {};

    // staging map (validated): row = tid>>2, global chunk = (tid&3)^((tid>>3)&3)
    const int srow = tid >> 2;
    const int fch  = (tid & 3) ^ ((tid >> 3) & 3);
    const ushort* gA = A + (size_t)(m0 + srow) * K_TOT + fch * 8;
    const ushort* gB = W + (size_t)(n0 + srow) * K_TOT + fch * 8;

#define GLDS(gptr, lptr) __builtin_amdgcn_global_load_lds(                     \
        (const __attribute__((address_space(1))) void*)(gptr),                 \
        (__attribute__((address_space(3))) void*)(lptr), 16, 0, 0)

#define STAGE(db, kt) do {                                                     \
    GLDS(gA + (size_t)(kt) * 32,                  &sA[db][tid * 8]);           \
    GLDS(gA + (size_t)128 * K_TOT + (size_t)(kt) * 32, &sA[db][4096 + tid * 8]); \
    GLDS(gB + (size_t)(kt) * 32,                  &sB[db][tid * 8]);           \
    GLDS(gB + (size_t)128 * K_TOT + (size_t)(kt) * 32, &sB[db][4096 + tid * 8]); \
} while (0)

    const int lrow = lane & 15;
    const int cb0  = lane >> 4;             // 0..3 k-chunk
    const int csw2 = (lrow >> 1) & 3;       // read-side swizzle (0-conflict)
    const unsigned aByte = (unsigned)(((wr * 128 + lrow) * 32 + ((cb0 ^ csw2) * 8)) * 2);
    const unsigned bByte = (unsigned)(((wcn * 64  + lrow) * 32 + ((cb0 ^ csw2) * 8)) * 2);

#define DSR(dst, addr, IMM) asm volatile(                                      \
    "ds_read_b128 %0, %1 offset:" IMM : "=&v"(dst) : "v"(addr))

#define READS(afX, bfX, db) do {                                               \
    unsigned aAd = (unsigned)(uintptr_t)                                       \
        (__attribute__((address_space(3))) ushort*)&sA[db][0] + aByte;         \
    unsigned bAd = (unsigned)(uintptr_t)                                       \
        (__attribute__((address_space(3))) ushort*)&sB[db][0] + bByte;         \
    i32x4 r0, r1, r2, r3, r4, r5, r6, r7, s0, s1, s2, s3;                      \
    DSR(r0, aAd, "0");    DSR(r1, aAd, "1024");                                \
    DSR(r2, aAd, "2048"); DSR(r3, aAd, "3072");                                \
    DSR(r4, aAd, "4096"); DSR(r5, aAd, "5120");                                \
    DSR(r6, aAd, "6144"); DSR(r7, aAd, "7168");                                \
    DSR(s0, bAd, "0");    DSR(s1, bAd, "1024");                                \
    DSR(s2, bAd, "2048"); DSR(s3, bAd, "3072");                                \
    afX[0] = as_bf(r0); afX[1] = as_bf(r1); afX[2] = as_bf(r2);                \
    afX[3] = as_bf(r3); afX[4] = as_bf(r4); afX[5] = as_bf(r5);                \
    afX[6] = as_bf(r6); afX[7] = as_bf(r7);                                    \
    bfX[0] = as_bf(s0); bfX[1] = as_bf(s1); bfX[2] = as_bf(s2);                \
    bfX[3] = as_bf(s3);                                                        \
} while (0)

#define WAITK(n) do {                                                          \
    asm volatile("s_waitcnt lgkmcnt(" #n ")");                                 \
    __builtin_amdgcn_sched_barrier(0);                                         \
} while (0)

#define MFMAS(afX, bfX) do {                                                   \
    __builtin_amdgcn_s_setprio(1);                                             \
    _Pragma("unroll")                                                          \
    for (int m = 0; m < 8; ++m)                                                \
        _Pragma("unroll")                                                      \
        for (int n = 0; n < 4; ++n)                                            \
            acc[m][n] = __builtin_amdgcn_mfma_f32_16x16x32_bf16(               \
                afX[m], bfX[n], acc[m][n], 0, 0, 0);                           \
    __builtin_amdgcn_s_setprio(0);                                             \
} while (0)

#define BARX() __builtin_amdgcn_s_barrier()
#define VMC(n) asm volatile("s_waitcnt vmcnt(" #n ")" ::: "memory")

    bf16x8 af0[8], bfv0[4], af1[8], bfv1[4];

    // prologue: stage tiles 0,1,2; retire 0,1; read tile-0 frags
    STAGE(0, 0); STAGE(1, 1); STAGE(2, 2);
    VMC(4);
    BARX();
    READS(af0, bfv0, 0);

    // tile t: STAGE(t+3) | READS(t+1) | lgkm(12) | MFMA(t) | VMC(4) | BAR
#define TILE(u, t, Fna, Fnb, Fca, Fcb) do {                                    \
    STAGE(((u) + 3) & 3, (t) + 3);                                             \
    READS(Fna, Fnb, ((u) + 1) & 3);                                            \
    WAITK(12);                                                                 \
    MFMAS(Fca, Fcb);                                                           \
    VMC(4);                                                                    \
    BARX();                                                                    \
} while (0)

    for (int hh = 0; hh < 11; ++hh) {
        const int t = hh * 4;
        TILE(0, t + 0, af1, bfv1, af0, bfv0);
        TILE(1, t + 1, af0, bfv0, af1, bfv1);
        TILE(2, t + 2, af1, bfv1, af0, bfv0);
        TILE(3, t + 3, af0, bfv0, af1, bfv1);
    }
    // peeled tail: t = 44..47
    TILE(0, 44, af1, bfv1, af0, bfv0);          // stages 47
    // t=45: no stage; VMC(0) retires S47 before t=46 reads buf3
    READS(af0, bfv0, 2);                        // tile 46 frags
    WAITK(12);
    MFMAS(af1, bfv1);                           // tile 45
    VMC(0);
    BARX();
    // t=46
    READS(af1, bfv1, 3);                        // tile 47 frags
    WAITK(12);
    MFMAS(af0, bfv0);                           // tile 46
    BARX();
    // t=47
    WAITK(0);
    MFMAS(af1, bfv1);                           // tile 47

    // epilogue: lane owns unit = by*64 + wcn*16 + lrow; gates = acc[m][0..3]
    const int unit = by * 64 + wcn * 16 + lrow;
    const float b0 = bias[unit];
    const float b1 = bias[1024 + unit];
    const float b2 = bias[2048 + unit];
    const float b3 = bias[3072 + unit];
    const int r0 = m0 + wr * 128 + (lane >> 4) * 4;
#pragma unroll
    for (int mi = 0; mi < 8; ++mi) {
#pragma unroll
        for (int q = 0; q < 4; ++q) {
            const int row = r0 + mi * 16 + q;
            const size_t off = (size_t)row * N_HID + unit;
            float zi = acc[mi][0][q] + b0;
            float zf = acc[mi][1][q] + b1;
            float zg = acc[mi][2][q] + b2;
            float zo = acc[mi][3][q] + b3;
            float it_ = sigmoid_f(zi);
            float ft = sigmoid_f(zf);
            float gt = tanh_f(zg);
            float ot = sigmoid_f(zo);
            float ct = ft * cin[off] + it_ * gt;
            float ht = ot * tanh_f(ct);
            outc[off] = ct;
            outh[off] = ht;
        }
    }
#undef GLDS
#undef STAGE
#undef DSR
#undef READS
#undef WAITK
#undef MFMAS
#undef BARX
#undef VMC
#undef TILE
}

// ---------------- launch ----------------

extern "C" void kernel_launch(void* const* d_in, const int* in_sizes, int n_in,
                              void* d_out, int out_size, void* d_ws, size_t ws_size,
                              hipStream_t stream) {
    const float* x = (const float*)d_in[0];
    const float* c = (const float*)d_in[1];
    const float* h = (const float*)d_in[2];
    const float* Wii = (const float*)d_in[3];  const float* bii = (const float*)d_in[4];
    const float* Wif = (const float*)d_in[5];  const float* bif = (const float*)d_in[6];
    const float* Wig = (const float*)d_in[7];  const float* big = (const float*)d_in[8];
    const float* Wio = (const float*)d_in[9];  const float* bio = (const float*)d_in[10];
    const float* Whi = (const float*)d_in[11]; const float* bhi = (const float*)d_in[12];
    const float* Whf = (const float*)d_in[13]; const float* bhf = (const float*)d_in[14];
    const float* Whg = (const float*)d_in[15]; const float* bhg = (const float*)d_in[16];
    const float* Who = (const float*)d_in[17]; const float* bho = (const float*)d_in[18];

    char* ws = (char*)d_ws;
    ushort* A_cat  = (ushort*)ws;                                   // 50,331,648 B
    ushort* W_perm = (ushort*)(ws + (size_t)M_ROWS * K_TOT * 2);    // 12,582,912 B
    float*  biasc  = (float*)(ws + (size_t)M_ROWS * K_TOT * 2
                                 + (size_t)N_TOT * K_TOT * 2);      // 16 KB

    float* outc = (float*)d_out;
    float* outh = (float*)d_out + (size_t)M_ROWS * N_HID;

    hipLaunchKernelGGL(prep_all, dim3(2048), dim3(256), 0, stream,
                       x, h,
                       Wii, Wif, Wig, Wio, Whi, Whf, Whg, Who,
                       bii, bif, big, bio, bhi, bhf, bhg, bho,
                       A_cat, W_perm, biasc);
    hipLaunchKernelGGL(lstm_gemm, dim3(1024), dim3(512), 0, stream,
                       A_cat, W_perm, biasc, c, outc, outh);
}